// Round 13
// baseline (44.373 us; speedup 1.0000x reference)
//
#include <hip/hip_runtime.h>
#include <hip/hip_bf16.h>

// Shapes (fixed): D=1, S=64, A=128, P=K=6, T=80
#define NS 64
#define NA 128
#define NK 6
#define NT 80

// Output layout (flat concat, float):
//   waymo_valid  [S,T,A]        655360
//   waymo_trajs  [S,T,A,K,2]    7864320
//   waymo_scores [S,A,K]        49152
//   waymo_yaw    [S,T,A,K,1]    3932160
#define OFF_TRAJ   655360
#define OFF_SCORE  (655360 + 7864320)
#define OFF_YAW    (655360 + 7864320 + 49152)

typedef float nfloat4 __attribute__((ext_vector_type(4)));

// ================= k_move: barrier-free shuffle transpose =================
// bid <  768 : traj role. wave job (s, rb of 16 rows), 10 iters over t-octs.
// bid < 1536 : yaw role.  wave job (s, rb of 16 rows), 5 iters over 16-t blocks.
// bid >=1536 : valid role (64 blocks, one scene each).
__global__ __launch_bounds__(256) void k_move(
    const int*    __restrict__ validIn,
    const float2* __restrict__ posIn,    // [S*A*K, T] float2 rows
    const float*  __restrict__ yawIn,    // [S*A*K, T] float rows
    float*        __restrict__ out)
{
    const int bid  = blockIdx.x;
    const int tid  = threadIdx.x;
    const int lane = tid & 63;

    if (bid < 768) {
        // -------- traj: rows pair-transposed via one shfl_xor(4) --------
        const int wj = bid * 4 + (tid >> 6);    // 0..3071 = (s, rb48)
        const int s  = wj / 48, rb = wj - s * 48;
        const int r  = lane >> 2;               // 0..15 row-in-block
        const int f  = lane & 3;                // 0..3 f4-in-line (t-oct slot)

        const nfloat4* in4  = (const nfloat4*)posIn;
        nfloat4*       out4 = (nfloat4*)(out + OFF_TRAJ);

        // input f4: row (s*768 + rb*16 + r), f4-index row*40 + it*4 + f
        size_t ib = (size_t)(s * 768 + rb * 16 + r) * 40 + f;
        // output: t = it*8 + 2f + (r&1); f4 = (s*80+t)*384 + rb*8 + (r>>1)
        size_t ob = (size_t)(s * 80 + 2 * f + (r & 1)) * 384 + rb * 8 + (r >> 1);

        #pragma unroll
        for (int it = 0; it < 10; ++it) {
            nfloat4 v = in4[ib + it * 4];
            nfloat4 x;
            x.x = __shfl_xor(v.x, 4);
            x.y = __shfl_xor(v.y, 4);
            x.z = __shfl_xor(v.z, 4);
            x.w = __shfl_xor(v.w, 4);
            nfloat4 w;
            if (r & 1) { w.x = x.z; w.y = x.w; w.z = v.z; w.w = v.w; }
            else       { w.x = v.x; w.y = v.y; w.z = x.x; w.w = x.y; }
            out4[ob + (size_t)it * 8 * 384] = w;
        }
    } else if (bid < 1536) {
        // -------- yaw: 4x4 in-wave butterfly transpose --------
        const int wj = (bid - 768) * 4 + (tid >> 6);  // 0..3071 = (s, rb48)
        const int s  = wj / 48, rb = wj - s * 48;
        const int r  = lane & 15;               // row-in-block
        const int c  = lane >> 4;               // t-quad slot 0..3

        const nfloat4* in4  = (const nfloat4*)yawIn;
        nfloat4*       out4 = (nfloat4*)(out + OFF_YAW);

        // input f4: row (s*768 + rb*16 + r), f4-index row*20 + tb*4 + c
        size_t ib = (size_t)(s * 768 + rb * 16 + r) * 20 + c;
        // output: t = tb*16 + c*4 + (r&3); f4 = (s*80+t)*192 + rb*4 + (r>>2)
        size_t ob = (size_t)(s * 80 + c * 4 + (r & 3)) * 192 + rb * 4 + (r >> 2);

        #pragma unroll
        for (int tb = 0; tb < 5; ++tb) {
            nfloat4 v = in4[ib + tb * 4];
            // stage A: xor 1
            nfloat4 a;
            a.x = __shfl_xor(v.x, 1); a.y = __shfl_xor(v.y, 1);
            a.z = __shfl_xor(v.z, 1); a.w = __shfl_xor(v.w, 1);
            nfloat4 u;
            if (r & 1) { u.x = a.y; u.y = v.y; u.z = a.w; u.w = v.w; }
            else       { u.x = v.x; u.y = a.x; u.z = v.z; u.w = a.z; }
            // stage B: xor 2
            nfloat4 b;
            b.x = __shfl_xor(u.x, 2); b.y = __shfl_xor(u.y, 2);
            b.z = __shfl_xor(u.z, 2); b.w = __shfl_xor(u.w, 2);
            nfloat4 o;
            if (r & 2) { o.x = b.z; o.y = b.w; o.z = u.z; o.w = u.w; }
            else       { o.x = u.x; o.y = u.y; o.z = b.x; o.w = b.y; }
            out4[ob + (size_t)tb * 16 * 192] = o;
        }
    } else {
        // -------- valid broadcast: one scene per block --------
        const int s = bid - 1536;
        __shared__ nfloat4 vrow[NA / 4];
        if (tid < 32) {
            const int bse = s * NA + 4 * tid;
            nfloat4 v;
            v.x = (validIn[bse + 0] != 0) ? 1.0f : 0.0f;
            v.y = (validIn[bse + 1] != 0) ? 1.0f : 0.0f;
            v.z = (validIn[bse + 2] != 0) ? 1.0f : 0.0f;
            v.w = (validIn[bse + 3] != 0) ? 1.0f : 0.0f;
            vrow[tid] = v;
        }
        __syncthreads();
        nfloat4* vOut = (nfloat4*)out;
        for (int o = tid; o < NT * 32; o += 256) {
            int t = o >> 5, q = o & 31;
            vOut[(size_t)(s * NT + t) * 32 + q] = vrow[q];
        }
    }
}

// ================= k_score: softmax + NMS (verified R11 logic) =================
#define SPS 82   // f2 row stride

__global__ __launch_bounds__(256) void k_score(
    const int*    __restrict__ validIn,
    const float*  __restrict__ confIn,
    const float2* __restrict__ posIn,
    const float*  __restrict__ typeIn,
    float*        __restrict__ out)
{
    const int g   = blockIdx.x;
    const int tid = threadIdx.x;
    const int s   = g >> 4;
    const int a0  = (g & 15) * 8;

    __shared__ float2 sPos[48 * SPS];   // 31.5 KB

    const float2* pbase = posIn + ((size_t)s * NA + a0) * (NK * NT);

    for (int i = tid; i < 1920; i += 256) {
        int r = i / 40, q = i - r * 40;
        nfloat4 v = *(const nfloat4*)(pbase + (size_t)r * NT + 2 * q);
        *(nfloat4*)&sPos[r * SPS + 2 * q] = v;
    }
    __syncthreads();

    const int la   = tid >> 5;
    const int lane = tid & 31;
    const int p    = lane >> 1;
    const int half = lane & 1;

    const size_t sa = (size_t)s * NA + a0 + la;
    const float th = 2.5f * typeIn[sa * 3 + 0]
                   + 1.0f * typeIn[sa * 3 + 1]
                   + 1.5f * typeIn[sa * 3 + 2];

    int pi, pj;
    if      (p < 5)  { pi = 0; pj = p + 1; }
    else if (p < 9)  { pi = 1; pj = p - 3; }
    else if (p < 12) { pi = 2; pj = p - 6; }
    else if (p < 14) { pi = 3; pj = p - 8; }
    else             { pi = 4; pj = 5;     }

    const int rI = la * NK + pi, rJ = la * NK + pj;
    float dsum = 0.f;
    for (int t = half * 40; t < half * 40 + 40; ++t) {
        float2 u = sPos[rI * SPS + t];
        float2 v = sPos[rJ * SPS + t];
        float dx = u.x - v.x, dy = u.y - v.y;
        dsum += sqrtf(dx * dx + dy * dy);
    }
    dsum += __shfl_xor(dsum, 1);
    const bool within = (dsum / 80.0f) < th;
    const bool predb  = (half == 0) && (p < 15) && within;
    unsigned long long bal = __ballot(predb);
    unsigned mask32 = (unsigned)(bal >> (tid & 32));

    if (lane == 0) {
        float c[NK];
        float mx = -3e38f;
        for (int q = 0; q < NK; ++q) { c[q] = confIn[sa * NK + q]; mx = fmaxf(mx, c[q]); }
        float ssum = 0.f;
        for (int q = 0; q < NK; ++q) { c[q] = expf(c[q] - mx); ssum += c[q]; }
        for (int q = 0; q < NK; ++q) c[q] /= ssum;
        ssum = 0.f;
        for (int q = 0; q < NK; ++q) ssum += c[q];
        for (int q = 0; q < NK; ++q) c[q] /= ssum;

        int ord[NK]; bool used[NK];
        for (int q = 0; q < NK; ++q) used[q] = false;
        for (int st = 0; st < NK; ++st) {
            int best = 0; float bv = -3e38f;
            for (int q = 0; q < NK; ++q)
                if (!used[q] && c[q] > bv) { bv = c[q]; best = q; }
            used[best] = true; ord[st] = best;
        }

        float cur[NK];
        for (int q = 0; q < NK; ++q) cur[q] = c[q];

        if (validIn[sa] != 0) {
            for (int st = 0; st < NK; ++st) {
                int k = ord[st];
                float ck = cur[k];
                bool any = false;
                for (int j = 0; j < NK; ++j) {
                    if (j == k) continue;
                    int lo = j < k ? j : k;
                    int hi = j < k ? k : j;
                    int pidx = lo * 5 - (lo * (lo - 1)) / 2 + (hi - lo - 1);
                    if (((mask32 >> (2 * pidx)) & 1u) && (cur[j] > ck)) any = true;
                }
                if (any) cur[k] = 0.001f;
            }
        }

        float tsum = 0.f;
        for (int q = 0; q < NK; ++q) tsum += cur[q];
        float w[NK]; float wsum = 0.f;
        for (int q = 0; q < NK; ++q) {
            float qq = cur[q] / tsum;
            w[q] = qq * qq; wsum += w[q];
        }
        float* outSc = out + OFF_SCORE;
        for (int q = 0; q < NK; ++q) outSc[sa * NK + q] = w[q] / wsum;
    }
}

extern "C" void kernel_launch(void* const* d_in, const int* in_sizes, int n_in,
                              void* d_out, int out_size, void* d_ws, size_t ws_size,
                              hipStream_t stream) {
    const int*    validIn = (const int*)d_in[0];
    const float*  confIn  = (const float*)d_in[1];
    const float2* posIn   = (const float2*)d_in[2];
    const float*  yawIn   = (const float*)d_in[3];
    const float*  typeIn  = (const float*)d_in[4];
    float* out = (float*)d_out;

    k_move<<<1600, 256, 0, stream>>>(validIn, posIn, yawIn, out);
    k_score<<<1024, 256, 0, stream>>>(validIn, confIn, posIn, typeIn, out);
}